// Round 5
// baseline (455.015 us; speedup 1.0000x reference)
//
#include <hip/hip_runtime.h>
#include <cstdint>

// GaussianAgg: z_map construction + S=16 perturbed argmaxes -> mean one-hot.
// HBM-bound: noise [16,131072,33] f32 = 277 MB read-once dominates (362 MB total
// -> ~57 us floor @ 6.3 TB/s). R3 post-mortem: kernel < 165 us (absent from
// rocprof top-5; harness ws-poison fills at 166 us dominate dur_us).
// R5 = R4 with native vector type for __builtin_nontemporal_load (HIP float4
// is a class -> rejected by the builtin). One barrier per sample, double LDS
// buffer, ping-pong register banks, prefetch issued before the vmcnt wait.

#define NPIX    131072
#define KCH     32
#define CCH     33               // K + background
#define SAMP    16
#define TPB     128
#define TILE_F  (TPB * CCH)      // 4224 floats = 16.9 KB per buffer
#define TILE_V4 (TILE_F / 4)     // 1056 vec4
#define FULL_J  (TILE_V4 / TPB)  // 8 full strided iterations
#define REM     (TILE_V4 % TPB)  // 32-thread tail

typedef float f4 __attribute__((ext_vector_type(4)));  // native vector: builtin-compatible

__global__ __launch_bounds__(TPB)
void gauss_agg_kernel(const float* __restrict__ zbuf,
                      const float* __restrict__ zfar_p,
                      const float* __restrict__ znear_p,
                      const float* __restrict__ prob,
                      const float* __restrict__ mask,
                      const float* __restrict__ noise,
                      float* __restrict__ out)
{
#pragma clang fp contract(off)
    __shared__ float buf[2][TILE_F];
    const int tid = threadIdx.x;
    const int p0  = blockIdx.x * TPB;
    const size_t p = (size_t)p0 + tid;

    const float zfar  = zfar_p[0];
    const float znear = znear_p[0];
    const float denom = zfar - znear;

    // ---- per-pixel input rows: 32 contiguous floats @128B-aligned base.
    float zb[KCH], pm[KCH], mk[KCH];
    {
        const f4* zb4 = reinterpret_cast<const f4*>(zbuf + p * KCH);
        const f4* pm4 = reinterpret_cast<const f4*>(prob + p * KCH);
        const f4* mk4 = reinterpret_cast<const f4*>(mask + p * KCH);
        #pragma unroll
        for (int i = 0; i < KCH / 4; ++i) {
            f4 a = zb4[i], b = pm4[i], c = mk4[i];
            #pragma unroll
            for (int q = 0; q < 4; ++q) {
                zb[4*i+q] = a[q]; pm[4*i+q] = b[q]; mk[4*i+q] = c[q];
            }
        }
    }

    // ---- prefetch noise tile(0) into register bank 0 (9 nt loads in flight)
    f4 r[2][FULL_J + 1];
    {
        const f4* g4 = reinterpret_cast<const f4*>(noise + (size_t)p0 * CCH);
        #pragma unroll
        for (int j = 0; j < FULL_J; ++j)
            r[0][j] = __builtin_nontemporal_load(&g4[tid + j * TPB]);
        if (tid < REM)
            r[0][FULL_J] = __builtin_nontemporal_load(&g4[tid + FULL_J * TPB]);
    }

    // ---- z_inv + zmax, then z_map (overlaps tile(0) loads; order matches ref)
    float z_inv[KCH];
    float zmax = 1e-10f;
    #pragma unroll
    for (int k = 0; k < KCH; ++k) {
        float zi = ((zfar - zb[k]) / denom) * mk[k];
        z_inv[k] = zi;
        zmax = fmaxf(zmax, zi);
    }
    float z_map[CCH];
    #pragma unroll
    for (int k = 0; k < KCH; ++k) {
        float lg = logf(1e-12f + pm[k]);
        z_map[k] = ((0.04f * lg) + z_inv[k]) - zmax;
    }
    z_map[KCH] = 1e-10f - zmax;

    int acc[CCH];
    #pragma unroll
    for (int c = 0; c < CCH; ++c) acc[c] = 0;

    // ---- sample loop, ONE barrier per iteration.
    //  iter s: prefetch tile(s+1) -> r[(s+1)&1]   (issued first, no wait)
    //          ds_write r[s&1] -> buf[s&1]        (vmcnt waits tile(s) only)
    //          __syncthreads()
    //          argmax from buf[s&1]
    //  Skew safety: fast wave in iter s+1 writes buf[(s+1)&1] while slowest
    //  reader is in buf[s&1] -> disjoint; barrier bounds skew to 1 iter.
    #pragma unroll
    for (int s = 0; s < SAMP; ++s) {
        const int cur = s & 1;
        if (s + 1 < SAMP) {
            const f4* g4 = reinterpret_cast<const f4*>(
                noise + ((size_t)(s + 1) * NPIX + p0) * CCH);
            #pragma unroll
            for (int j = 0; j < FULL_J; ++j)
                r[cur ^ 1][j] = __builtin_nontemporal_load(&g4[tid + j * TPB]);
            if (tid < REM)
                r[cur ^ 1][FULL_J] =
                    __builtin_nontemporal_load(&g4[tid + FULL_J * TPB]);
        }
        {
            f4* l4 = reinterpret_cast<f4*>(buf[cur]);
            #pragma unroll
            for (int j = 0; j < FULL_J; ++j) l4[tid + j * TPB] = r[cur][j];
            if (tid < REM) l4[tid + FULL_J * TPB] = r[cur][FULL_J];
        }
        __syncthreads();

        // first-max argmax (strict >); own row, 2-way bank alias = free (m136)
        const float* nb = buf[cur] + tid * CCH;
        float best = z_map[0] + (0.04f * nb[0]);
        int bi = 0;
        #pragma unroll
        for (int c = 1; c < CCH; ++c) {
            float v = z_map[c] + (0.04f * nb[c]);
            if (v > best) { best = v; bi = c; }
        }
        #pragma unroll
        for (int c = 0; c < CCH; ++c) acc[c] += (bi == c);
    }

    // ---- epilogue: counts/16 via buf[0] (safe: all waves past barrier(15);
    // buf[0] has no readers after iter 14), coalesced vec4 stores
    {
        const int rb = tid * CCH;
        #pragma unroll
        for (int c = 0; c < CCH; ++c) buf[0][rb + c] = (float)acc[c] * 0.0625f;
    }
    __syncthreads();
    {
        const f4* l4 = reinterpret_cast<const f4*>(buf[0]);
        f4* o4 = reinterpret_cast<f4*>(out + (size_t)p0 * CCH);
        #pragma unroll
        for (int j = 0; j < FULL_J; ++j) o4[tid + j * TPB] = l4[tid + j * TPB];
        if (tid < REM) o4[tid + FULL_J * TPB] = l4[tid + FULL_J * TPB];
    }
}

extern "C" void kernel_launch(void* const* d_in, const int* in_sizes, int n_in,
                              void* d_out, int out_size, void* d_ws, size_t ws_size,
                              hipStream_t stream)
{
    const float* zbuf  = (const float*)d_in[0];
    const float* zfar  = (const float*)d_in[1];
    const float* znear = (const float*)d_in[2];
    const float* prob  = (const float*)d_in[3];
    const float* mask  = (const float*)d_in[4];
    const float* noise = (const float*)d_in[5];
    float* out = (float*)d_out;

    dim3 grid(NPIX / TPB), block(TPB);
    gauss_agg_kernel<<<grid, block, 0, stream>>>(zbuf, zfar, znear, prob, mask,
                                                 noise, out);
}